// Round 2
// baseline (388243.481 us; speedup 1.0000x reference)
//
#include <hip/hip_runtime.h>
#include <math.h>

#define H 128
#define NN 100000
#define E_AST 100000
#define E_MST 20000
#define E_TOT 240000
#define NV 30000
#define NP 8000
#define N4 400000
#define NH 12800000   // NN * H

// ---------------- embedding lookup -> h ----------------
__global__ void embed_kernel(const int* __restrict__ ids, const float* __restrict__ emb,
                             float* __restrict__ h) {
    int g = blockIdx.x * 256 + threadIdx.x;
    if (g >= NN * 64) return;
    int i = g >> 6, j2 = (g & 63) << 1;
    *(float2*)&h[(size_t)i * H + j2] = *(const float2*)&emb[(size_t)ids[i] * H + j2];
}

// ---------------- CSR build over keys (tgt*4 + e) ----------------
__device__ inline void edge_decode(int t, const int* __restrict__ ast, const int* __restrict__ mst,
                                   int& e, int& src, int& tgt) {
    if (t < E_AST)                 { e = 0; src = ast[2*t];     tgt = ast[2*t+1]; }
    else if (t < 2*E_AST)          { int i = t - E_AST;         e = 1; src = ast[2*i+1]; tgt = ast[2*i]; }
    else if (t < 2*E_AST + E_MST)  { int i = t - 2*E_AST;       e = 2; src = mst[2*i];   tgt = mst[2*i+1]; }
    else                           { int i = t - 2*E_AST-E_MST; e = 3; src = mst[2*i+1]; tgt = mst[2*i]; }
}

__global__ void count4_kernel(const int* __restrict__ ast, const int* __restrict__ mst,
                              int* __restrict__ deg4) {
    int t = blockIdx.x * 256 + threadIdx.x;
    if (t >= E_TOT) return;
    int e, src, tgt; edge_decode(t, ast, mst, e, src, tgt);
    atomicAdd(&deg4[tgt * 4 + e], 1);
}

// exclusive scan over N4 elements, 2048 per block (256 thr x 8)
__global__ void scan1b(const int* __restrict__ deg, int* __restrict__ excl,
                       int* __restrict__ partial, int n) {
    __shared__ int sm[256];
    int t = threadIdx.x, b = blockIdx.x;
    int base = b * 2048 + t * 8;
    int v[8]; int s = 0;
    #pragma unroll
    for (int i = 0; i < 8; ++i) { v[i] = (base + i < n) ? deg[base + i] : 0; s += v[i]; }
    sm[t] = s;
    __syncthreads();
    for (int off = 1; off < 256; off <<= 1) {
        int x = (t >= off) ? sm[t - off] : 0;
        __syncthreads();
        sm[t] += x;
        __syncthreads();
    }
    int run = sm[t] - s;
    if (t == 255) partial[b] = sm[255];
    #pragma unroll
    for (int i = 0; i < 8; ++i) {
        if (base + i < n) { excl[base + i] = run; run += v[i]; }
    }
}

__global__ void scan2(int* __restrict__ partial, int nb) {
    __shared__ int sm[256];
    int t = threadIdx.x;
    int v = (t < nb) ? partial[t] : 0;
    sm[t] = v;
    __syncthreads();
    for (int off = 1; off < 256; off <<= 1) {
        int x = (t >= off) ? sm[t - off] : 0;
        __syncthreads();
        sm[t] += x;
        __syncthreads();
    }
    if (t < nb) partial[t] = sm[t] - v;   // exclusive
}

__global__ void scan3b(int* __restrict__ rp, const int* __restrict__ partial, int n, int etot) {
    int i = blockIdx.x * 256 + threadIdx.x;
    if (i < n) rp[i] += partial[i >> 11];
    if (i == n) rp[n] = etot;
}

__global__ void fill4_kernel(const int* __restrict__ ast, const int* __restrict__ mst,
                             const int* __restrict__ rp4, int* __restrict__ cnt4,
                             int* __restrict__ col) {
    int t = blockIdx.x * 256 + threadIdx.x;
    if (t >= E_TOT) return;
    int e, src, tgt; edge_decode(t, ast, mst, e, src, tgt);
    int key = tgt * 4 + e;
    int slot = rp4[key] + atomicAdd(&cnt4[key], 1);
    col[slot] = src;
}

// ---------------- incoming = sum_e deg4[t][e] * msg_b[layer][e][:] ----------------
__global__ void init_inc(const int* __restrict__ deg4, const float* __restrict__ mb,
                         float* __restrict__ inc) {
    int g = blockIdx.x * 256 + threadIdx.x;
    if (g >= NN * 64) return;
    int i = g >> 6, j2 = (g & 63) << 1;
    float d0 = (float)deg4[i*4+0], d1 = (float)deg4[i*4+1];
    float d2 = (float)deg4[i*4+2], d3 = (float)deg4[i*4+3];
    float2 m0 = *(const float2*)&mb[0*H + j2];
    float2 m1 = *(const float2*)&mb[1*H + j2];
    float2 m2 = *(const float2*)&mb[2*H + j2];
    float2 m3 = *(const float2*)&mb[3*H + j2];
    float2 o;
    o.x = d0*m0.x + d1*m1.x + d2*m2.x + d3*m3.x;
    o.y = d0*m0.y + d1*m1.y + d2*m2.y + d3*m3.y;
    *(float2*)&inc[(size_t)i * H + j2] = o;
}

// ---------------- agg[t] = sum over in-edges of type e of h[src] ----------------
__global__ void gather_agg(const float* __restrict__ h, const int* __restrict__ rp4,
                           const int* __restrict__ col, int e, float* __restrict__ agg) {
    int wave = threadIdx.x >> 6, lane = threadIdx.x & 63;
    int t = blockIdx.x * 4 + wave;
    if (t >= NN) return;
    int r4 = t * 4 + e;
    int s0 = rp4[r4], s1 = rp4[r4 + 1];
    float2 acc = make_float2(0.f, 0.f);
    for (int s = s0; s < s1; ++s) {
        int src = col[s];
        float2 v = *(const float2*)&h[(size_t)src * H + lane * 2];
        acc.x += v.x; acc.y += v.y;
    }
    *(float2*)&agg[(size_t)t * H + lane * 2] = acc;
}

// ---------------- C[M x 128] += A[M x 128] @ B[128 x 128]^T ----------------
__global__ __launch_bounds__(256) void gemm_acc(
    const float* __restrict__ A, const float* __restrict__ B, float* __restrict__ C, int M)
{
    __shared__ float As[32][68];
    __shared__ float Bs[32][68];
    int tid = threadIdx.x, tx = tid & 15, ty = tid >> 4;
    int m0 = blockIdx.x * 64, n0 = blockIdx.y * 64;
    float acc[4][4] = {};
    for (int k0 = 0; k0 < 128; k0 += 32) {
        #pragma unroll
        for (int q = 0; q < 2; ++q) {
            int idx = q * 256 + tid, rr = idx >> 3, c4 = (idx & 7) << 2;
            int gr = m0 + rr;
            float4 v = make_float4(0.f, 0.f, 0.f, 0.f);
            if (gr < M) v = *(const float4*)&A[(size_t)gr * 128 + k0 + c4];
            As[c4+0][rr] = v.x; As[c4+1][rr] = v.y; As[c4+2][rr] = v.z; As[c4+3][rr] = v.w;
        }
        #pragma unroll
        for (int q = 0; q < 2; ++q) {
            int idx = q * 256 + tid, rr = idx >> 3, c4 = (idx & 7) << 2;
            float4 v = *(const float4*)&B[(size_t)(n0 + rr) * 128 + k0 + c4];
            Bs[c4+0][rr] = v.x; Bs[c4+1][rr] = v.y; Bs[c4+2][rr] = v.z; Bs[c4+3][rr] = v.w;
        }
        __syncthreads();
        #pragma unroll
        for (int k = 0; k < 32; ++k) {
            const float4 a = *(const float4*)&As[k][ty * 4];
            const float4 b = *(const float4*)&Bs[k][tx * 4];
            acc[0][0] += a.x*b.x; acc[0][1] += a.x*b.y; acc[0][2] += a.x*b.z; acc[0][3] += a.x*b.w;
            acc[1][0] += a.y*b.x; acc[1][1] += a.y*b.y; acc[1][2] += a.y*b.z; acc[1][3] += a.y*b.w;
            acc[2][0] += a.z*b.x; acc[2][1] += a.z*b.y; acc[2][2] += a.z*b.z; acc[2][3] += a.z*b.w;
            acc[3][0] += a.w*b.x; acc[3][1] += a.w*b.y; acc[3][2] += a.w*b.z; acc[3][3] += a.w*b.w;
        }
        __syncthreads();
    }
    #pragma unroll
    for (int i = 0; i < 4; ++i) {
        int gr = m0 + ty * 4 + i;
        if (gr >= M) continue;
        float4 o = *(float4*)&C[(size_t)gr * 128 + n0 + tx * 4];
        o.x += acc[i][0]; o.y += acc[i][1]; o.z += acc[i][2]; o.w += acc[i][3];
        *(float4*)&C[(size_t)gr * 128 + n0 + tx * 4] = o;
    }
}

// ---------------- fused GRU: gi/gh in-register, h updated in place ----------------
// RES: 0 = none (Kin=128), 1 = residual from emb[ids] (Kin=256), 2 = residual from s1 (Kin=256)
template<int RES>
__global__ __launch_bounds__(256) void fused_gru(
    const float* __restrict__ inc, const float* __restrict__ s1,
    const int* __restrict__ ids, const float* __restrict__ emb,
    float* h,
    const float* __restrict__ Wih, const float* __restrict__ Whh,
    const float* __restrict__ bihL, const float* __restrict__ bhhL)
{
    constexpr int Kin = (RES == 0) ? 128 : 256;
    constexpr int K4  = Kin / 4;
    constexpr int LK4 = (RES == 0) ? 5 : 6;
    __shared__ float sx[16][Kin + 4];
    __shared__ float shh[16][132];
    __shared__ float sw[32][Kin + 4];

    int t = threadIdx.x;
    int m0 = blockIdx.x * 16;     // 6250 * 16 == 100000, no tail

    // stage x = [incoming | res] and old h
    #pragma unroll
    for (int q = 0; q < 2; ++q) {
        int idx = q * 256 + t, row = idx >> 5, kc = idx & 31;
        *(float4*)&sx[row][kc * 4]  = *(const float4*)&inc[(size_t)(m0 + row) * H + kc * 4];
        *(float4*)&shh[row][kc * 4] = *(const float4*)&h[(size_t)(m0 + row) * H + kc * 4];
        if (RES == 1)
            *(float4*)&sx[row][128 + kc * 4] = *(const float4*)&emb[(size_t)ids[m0 + row] * H + kc * 4];
        if (RES == 2)
            *(float4*)&sx[row][128 + kc * 4] = *(const float4*)&s1[(size_t)(m0 + row) * H + kc * 4];
    }

    int r = t >> 4, l0 = (t & 15) * 2;
    float ai[12][2];   // gi pre-activations: chunk ch covers Wih rows [ch*32, ch*32+32)
    float ah[12][2];   // gh pre-activations
    __syncthreads();

    #pragma unroll
    for (int ch = 0; ch < 12; ++ch) {
        #pragma unroll
        for (int q = 0; q < K4 / 8; ++q) {
            int idx = q * 256 + t, row = idx >> LK4, kc = idx & (K4 - 1);
            *(float4*)&sw[row][kc * 4] = *(const float4*)&Wih[(size_t)(ch * 32 + row) * Kin + kc * 4];
        }
        __syncthreads();
        const float4* xr = (const float4*)&sx[r][0];
        const float4* w0 = (const float4*)&sw[l0][0];
        const float4* w1 = (const float4*)&sw[l0 + 1][0];
        float a0 = 0.f, a1 = 0.f;
        for (int k = 0; k < K4; ++k) {
            float4 a = xr[k]; float4 b0 = w0[k]; float4 b1 = w1[k];
            a0 += a.x*b0.x + a.y*b0.y + a.z*b0.z + a.w*b0.w;
            a1 += a.x*b1.x + a.y*b1.y + a.z*b1.z + a.w*b1.w;
        }
        ai[ch][0] = a0; ai[ch][1] = a1;
        __syncthreads();
    }

    #pragma unroll
    for (int ch = 0; ch < 12; ++ch) {
        #pragma unroll
        for (int q = 0; q < 4; ++q) {
            int idx = q * 256 + t, row = idx >> 5, kc = idx & 31;
            *(float4*)&sw[row][kc * 4] = *(const float4*)&Whh[(size_t)(ch * 32 + row) * H + kc * 4];
        }
        __syncthreads();
        const float4* xr = (const float4*)&shh[r][0];
        const float4* w0 = (const float4*)&sw[l0][0];
        const float4* w1 = (const float4*)&sw[l0 + 1][0];
        float a0 = 0.f, a1 = 0.f;
        for (int k = 0; k < 32; ++k) {
            float4 a = xr[k]; float4 b0 = w0[k]; float4 b1 = w1[k];
            a0 += a.x*b0.x + a.y*b0.y + a.z*b0.z + a.w*b0.w;
            a1 += a.x*b1.x + a.y*b1.y + a.z*b1.z + a.w*b1.w;
        }
        ah[ch][0] = a0; ah[ch][1] = a1;
        __syncthreads();
    }

    // GRU epilogue
    int gr = m0 + r;
    #pragma unroll
    for (int jb = 0; jb < 4; ++jb) {
        float o2[2];
        #pragma unroll
        for (int d = 0; d < 2; ++d) {
            int j = jb * 32 + l0 + d;
            float ir  = ai[jb][d]     + bihL[j];
            float iz  = ai[4 + jb][d] + bihL[128 + j];
            float inn = ai[8 + jb][d] + bihL[256 + j];
            float hr  = ah[jb][d]     + bhhL[j];
            float hz  = ah[4 + jb][d] + bhhL[128 + j];
            float hn  = ah[8 + jb][d] + bhhL[256 + j];
            float ho  = shh[r][j];
            float rg = 1.f / (1.f + __expf(-(ir + hr)));
            float zg = 1.f / (1.f + __expf(-(iz + hz)));
            float ng = tanhf(inn + rg * hn);
            o2[d] = (1.f - zg) * ng + zg * ho;
        }
        *(float2*)&h[(size_t)gr * H + jb * 32 + l0] = make_float2(o2[0], o2[1]);
    }
}

// ---------------- output gathers ----------------
__global__ void out_gather(const float* __restrict__ h, const int* __restrict__ idx,
                           float* __restrict__ out, int n) {
    int g = blockIdx.x * 256 + threadIdx.x;
    if (g >= n * 64) return;
    int v = g >> 6, j2 = (g & 63) << 1;
    *(float2*)&out[(size_t)v * H + j2] = *(const float2*)&h[(size_t)idx[v] * H + j2];
}

extern "C" void kernel_launch(void* const* d_in, const int* in_sizes, int n_in,
                              void* d_out, int out_size, void* d_ws, size_t ws_size,
                              hipStream_t stream) {
    const int*   ids    = (const int*)d_in[0];
    const int*   ast    = (const int*)d_in[1];
    const int*   mst    = (const int*)d_in[2];
    const int*   varpos = (const int*)d_in[3];
    const int*   predid = (const int*)d_in[4];
    const float* emb    = (const float*)d_in[5];
    const float* msg_W  = (const float*)d_in[6];   // [4][4][128][128]
    const float* msg_b  = (const float*)d_in[7];   // [4][4][128]
    const float* Wih_a  = (const float*)d_in[8];   // [2][384][128]
    const float* Wih_b  = (const float*)d_in[9];   // [2][384][256]
    const float* Whh    = (const float*)d_in[10];  // [4][384][128]
    const float* bih    = (const float*)d_in[11];  // [4][384]
    const float* bhh    = (const float*)d_in[12];  // [4][384]

    float* out = (float*)d_out;
    float* h   = out;                         // [NN][H] lives in d_out; final value IS output 0

    // CSR ints live in d_out tail (dead before final out_gathers overwrite it)
    int* ibase = (int*)(out + NH);
    int* deg4  = ibase;                       // 400000
    int* rp4   = ibase + 400000;              // 400001
    int* cnt4  = ibase + 800001;              // 400000
    int* col   = ibase + 1200001;             // 240000
    int* part  = ibase + 1440001;             // 256

    // workspace: 3 * NH floats = 153.6 MB
    if (ws_size < (size_t)3 * NH * sizeof(float)) return;   // absmax-fail (not crash) if too small
    float* W   = (float*)d_ws;
    float* s1  = W;                           // h after layer 0 (residual for layer 3)
    float* inc = W + NH;
    float* agg = W + 2 * (size_t)NH;

    embed_kernel<<<25000, 256, 0, stream>>>(ids, emb, h);

    hipMemsetAsync(deg4, 0, N4 * sizeof(int), stream);
    hipMemsetAsync(cnt4, 0, N4 * sizeof(int), stream);
    count4_kernel<<<(E_TOT + 255) / 256, 256, 0, stream>>>(ast, mst, deg4);
    scan1b<<<196, 256, 0, stream>>>(deg4, rp4, part, N4);
    scan2<<<1, 256, 0, stream>>>(part, 196);
    scan3b<<<1563, 256, 0, stream>>>(rp4, part, N4, E_TOT);
    fill4_kernel<<<(E_TOT + 255) / 256, 256, 0, stream>>>(ast, mst, rp4, cnt4, col);

    const int LT[4] = {5, 2, 5, 2};
    for (int layer = 0; layer < 4; ++layer) {
        const float* WihL;
        int resMode;
        if      (layer == 0) { WihL = Wih_a;                    resMode = 0; }
        else if (layer == 1) { WihL = Wih_b;                    resMode = 1; }
        else if (layer == 2) { WihL = Wih_a + (size_t)384*128;  resMode = 0; }
        else                 { WihL = Wih_b + (size_t)384*256;  resMode = 2; }
        const float* WhhL = Whh + (size_t)layer * 384 * 128;
        const float* bihL = bih + layer * 384;
        const float* bhhL = bhh + layer * 384;
        const float* mbL  = msg_b + (size_t)layer * 512;

        for (int ts = 0; ts < LT[layer]; ++ts) {
            init_inc<<<25000, 256, 0, stream>>>(deg4, mbL, inc);
            for (int e = 0; e < 4; ++e) {
                gather_agg<<<25000, 256, 0, stream>>>(h, rp4, col, e, agg);
                gemm_acc<<<dim3(1563, 2), 256, 0, stream>>>(
                    agg, msg_W + ((size_t)layer * 4 + e) * 128 * 128, inc, NN);
            }
            if (resMode == 0)
                fused_gru<0><<<6250, 256, 0, stream>>>(inc, s1, ids, emb, h, WihL, WhhL, bihL, bhhL);
            else if (resMode == 1)
                fused_gru<1><<<6250, 256, 0, stream>>>(inc, s1, ids, emb, h, WihL, WhhL, bihL, bhhL);
            else
                fused_gru<2><<<6250, 256, 0, stream>>>(inc, s1, ids, emb, h, WihL, WhhL, bihL, bhhL);
        }
        if (layer == 0)
            hipMemcpyAsync(s1, h, (size_t)NH * sizeof(float), hipMemcpyDeviceToDevice, stream);
    }

    // outputs 1 and 2 (h already in place as output 0); these overwrite the dead int scratch
    out_gather<<<(NV * 64 + 255) / 256, 256, 0, stream>>>(h, varpos, out + NH, NV);
    out_gather<<<(NP * 64 + 255) / 256, 256, 0, stream>>>(h, predid, out + NH + (size_t)NV * H, NP);
}

// Round 3
// 10451.302 us; speedup vs baseline: 37.1479x; 37.1479x over previous
//
#include <hip/hip_runtime.h>
#include <hip/hip_bf16.h>
#include <math.h>

#define H 128
#define NN 100000
#define E_AST 100000
#define E_MST 20000
#define E_TOT 240000
#define NV 30000
#define NP 8000
#define N4 400000
#define NH 12800000   // NN * H

// ---------------- embedding lookup -> h ----------------
__global__ void embed_kernel(const int* __restrict__ ids, const float* __restrict__ emb,
                             float* __restrict__ h) {
    int g = blockIdx.x * 256 + threadIdx.x;
    if (g >= NN * 64) return;
    int i = g >> 6, j2 = (g & 63) << 1;
    *(float2*)&h[(size_t)i * H + j2] = *(const float2*)&emb[(size_t)ids[i] * H + j2];
}

// ---------------- CSR build over keys (tgt*4 + e) ----------------
__device__ inline void edge_decode(int t, const int* __restrict__ ast, const int* __restrict__ mst,
                                   int& e, int& src, int& tgt) {
    if (t < E_AST)                 { e = 0; src = ast[2*t];     tgt = ast[2*t+1]; }
    else if (t < 2*E_AST)          { int i = t - E_AST;         e = 1; src = ast[2*i+1]; tgt = ast[2*i]; }
    else if (t < 2*E_AST + E_MST)  { int i = t - 2*E_AST;       e = 2; src = mst[2*i];   tgt = mst[2*i+1]; }
    else                           { int i = t - 2*E_AST-E_MST; e = 3; src = mst[2*i+1]; tgt = mst[2*i]; }
}

__global__ void count4_kernel(const int* __restrict__ ast, const int* __restrict__ mst,
                              int* __restrict__ deg4) {
    int t = blockIdx.x * 256 + threadIdx.x;
    if (t >= E_TOT) return;
    int e, src, tgt; edge_decode(t, ast, mst, e, src, tgt);
    atomicAdd(&deg4[tgt * 4 + e], 1);
}

__global__ void scan1b(const int* __restrict__ deg, int* __restrict__ excl,
                       int* __restrict__ partial, int n) {
    __shared__ int sm[256];
    int t = threadIdx.x, b = blockIdx.x;
    int base = b * 2048 + t * 8;
    int v[8]; int s = 0;
    #pragma unroll
    for (int i = 0; i < 8; ++i) { v[i] = (base + i < n) ? deg[base + i] : 0; s += v[i]; }
    sm[t] = s;
    __syncthreads();
    for (int off = 1; off < 256; off <<= 1) {
        int x = (t >= off) ? sm[t - off] : 0;
        __syncthreads();
        sm[t] += x;
        __syncthreads();
    }
    int run = sm[t] - s;
    if (t == 255) partial[b] = sm[255];
    #pragma unroll
    for (int i = 0; i < 8; ++i) {
        if (base + i < n) { excl[base + i] = run; run += v[i]; }
    }
}

__global__ void scan2(int* __restrict__ partial, int nb) {
    __shared__ int sm[256];
    int t = threadIdx.x;
    int v = (t < nb) ? partial[t] : 0;
    sm[t] = v;
    __syncthreads();
    for (int off = 1; off < 256; off <<= 1) {
        int x = (t >= off) ? sm[t - off] : 0;
        __syncthreads();
        sm[t] += x;
        __syncthreads();
    }
    if (t < nb) partial[t] = sm[t] - v;
}

__global__ void scan3b(int* __restrict__ rp, const int* __restrict__ partial, int n, int etot) {
    int i = blockIdx.x * 256 + threadIdx.x;
    if (i < n) rp[i] += partial[i >> 11];
    if (i == n) rp[n] = etot;
}

__global__ void fill4_kernel(const int* __restrict__ ast, const int* __restrict__ mst,
                             const int* __restrict__ rp4, int* __restrict__ cnt4,
                             int* __restrict__ col) {
    int t = blockIdx.x * 256 + threadIdx.x;
    if (t >= E_TOT) return;
    int e, src, tgt; edge_decode(t, ast, mst, e, src, tgt);
    int key = tgt * 4 + e;
    int slot = rp4[key] + atomicAdd(&cnt4[key], 1);
    col[slot] = src;
}

// ---------------- incoming init: deg-weighted per-edge-type biases ----------------
__global__ void init_inc(const int* __restrict__ deg4, const float* __restrict__ mb,
                         float* __restrict__ inc) {
    int g = blockIdx.x * 256 + threadIdx.x;
    if (g >= NN * 64) return;
    int i = g >> 6, j2 = (g & 63) << 1;
    float d0 = (float)deg4[i*4+0], d1 = (float)deg4[i*4+1];
    float d2 = (float)deg4[i*4+2], d3 = (float)deg4[i*4+3];
    float2 m0 = *(const float2*)&mb[0*H + j2];
    float2 m1 = *(const float2*)&mb[1*H + j2];
    float2 m2 = *(const float2*)&mb[2*H + j2];
    float2 m3 = *(const float2*)&mb[3*H + j2];
    float2 o;
    o.x = d0*m0.x + d1*m1.x + d2*m2.x + d3*m3.x;
    o.y = d0*m0.y + d1*m1.y + d2*m2.y + d3*m3.y;
    *(float2*)&inc[(size_t)i * H + j2] = o;
}

// ---------------- agg[t] = sum over in-edges of type e of h[src] ----------------
__global__ void gather_agg(const float* __restrict__ h, const int* __restrict__ rp4,
                           const int* __restrict__ col, int e, float* __restrict__ agg) {
    int wave = threadIdx.x >> 6, lane = threadIdx.x & 63;
    int t = blockIdx.x * 4 + wave;
    if (t >= NN) return;
    int r4 = t * 4 + e;
    int s0 = rp4[r4], s1 = rp4[r4 + 1];
    float2 acc = make_float2(0.f, 0.f);
    for (int s = s0; s < s1; ++s) {
        int src = col[s];
        float2 v = *(const float2*)&h[(size_t)src * H + lane * 2];
        acc.x += v.x; acc.y += v.y;
    }
    *(float2*)&agg[(size_t)t * H + lane * 2] = acc;
}

// ---------------- C[M x 128] += A[M x 128] @ B[128 x 128]^T ----------------
__global__ __launch_bounds__(256) void gemm_acc(
    const float* __restrict__ A, const float* __restrict__ B, float* __restrict__ C, int M)
{
    __shared__ float As[32][68];
    __shared__ float Bs[32][68];
    int tid = threadIdx.x, tx = tid & 15, ty = tid >> 4;
    int m0 = blockIdx.x * 64, n0 = blockIdx.y * 64;
    float acc[4][4] = {};
    for (int k0 = 0; k0 < 128; k0 += 32) {
        #pragma unroll
        for (int q = 0; q < 2; ++q) {
            int idx = q * 256 + tid, rr = idx >> 3, c4 = (idx & 7) << 2;
            int gr = m0 + rr;
            float4 v = make_float4(0.f, 0.f, 0.f, 0.f);
            if (gr < M) v = *(const float4*)&A[(size_t)gr * 128 + k0 + c4];
            As[c4+0][rr] = v.x; As[c4+1][rr] = v.y; As[c4+2][rr] = v.z; As[c4+3][rr] = v.w;
        }
        #pragma unroll
        for (int q = 0; q < 2; ++q) {
            int idx = q * 256 + tid, rr = idx >> 3, c4 = (idx & 7) << 2;
            float4 v = *(const float4*)&B[(size_t)(n0 + rr) * 128 + k0 + c4];
            Bs[c4+0][rr] = v.x; Bs[c4+1][rr] = v.y; Bs[c4+2][rr] = v.z; Bs[c4+3][rr] = v.w;
        }
        __syncthreads();
        #pragma unroll
        for (int k = 0; k < 32; ++k) {
            const float4 a = *(const float4*)&As[k][ty * 4];
            const float4 b = *(const float4*)&Bs[k][tx * 4];
            acc[0][0] += a.x*b.x; acc[0][1] += a.x*b.y; acc[0][2] += a.x*b.z; acc[0][3] += a.x*b.w;
            acc[1][0] += a.y*b.x; acc[1][1] += a.y*b.y; acc[1][2] += a.y*b.z; acc[1][3] += a.y*b.w;
            acc[2][0] += a.z*b.x; acc[2][1] += a.z*b.y; acc[2][2] += a.z*b.z; acc[2][3] += a.z*b.w;
            acc[3][0] += a.w*b.x; acc[3][1] += a.w*b.y; acc[3][2] += a.w*b.z; acc[3][3] += a.w*b.w;
        }
        __syncthreads();
    }
    #pragma unroll
    for (int i = 0; i < 4; ++i) {
        int gr = m0 + ty * 4 + i;
        if (gr >= M) continue;
        float4 o = *(float4*)&C[(size_t)gr * 128 + n0 + tx * 4];
        o.x += acc[i][0]; o.y += acc[i][1]; o.z += acc[i][2]; o.w += acc[i][3];
        *(float4*)&C[(size_t)gr * 128 + n0 + tx * 4] = o;
    }
}

// ---------------- rz: r,z = sigmoid([inc|res] @ Wih[0:256]^T + h @ Whh[0:256]^T + b) ----------------
// 3-part K-concat GEMM (each part K=128). Tile 64x64, grid (1563, 4).
template<bool BF>
__global__ __launch_bounds__(256) void rz_kernel(
    const float* __restrict__ inc,
    const float* __restrict__ res, const int* __restrict__ residx,
    const float* __restrict__ h,
    const float* __restrict__ Wih, int ldb,
    const float* __restrict__ Whh,
    const float* __restrict__ bihL, const float* __restrict__ bhhL,
    void* __restrict__ Rp, void* __restrict__ Zp)
{
    __shared__ float As[32][68];
    __shared__ float Bs[32][68];
    int tid = threadIdx.x, tx = tid & 15, ty = tid >> 4;
    int m0 = blockIdx.x * 64, n0 = blockIdx.y * 64;
    float acc[4][4] = {};
    int nparts = res ? 3 : 2;
    for (int p = 0; p < nparts; ++p) {
        const float* A; const int* idx = nullptr; const float* B; int bs;
        if (p == nparts - 1)  { A = h;   B = Whh;       bs = 128; }
        else if (p == 0)      { A = inc; B = Wih;       bs = ldb; }
        else                  { A = res; idx = residx; B = Wih + 128; bs = ldb; }
        for (int k0 = 0; k0 < 128; k0 += 32) {
            #pragma unroll
            for (int q = 0; q < 2; ++q) {
                int id2 = q * 256 + tid, rr = id2 >> 3, c4 = (id2 & 7) << 2;
                int gr = m0 + rr;
                float4 v = make_float4(0.f, 0.f, 0.f, 0.f);
                if (gr < NN) {
                    const float* base = idx ? A + (size_t)idx[gr] * H : A + (size_t)gr * H;
                    v = *(const float4*)&base[k0 + c4];
                }
                As[c4+0][rr] = v.x; As[c4+1][rr] = v.y; As[c4+2][rr] = v.z; As[c4+3][rr] = v.w;
            }
            #pragma unroll
            for (int q = 0; q < 2; ++q) {
                int id2 = q * 256 + tid, rr = id2 >> 3, c4 = (id2 & 7) << 2;
                float4 v = *(const float4*)&B[(size_t)(n0 + rr) * bs + k0 + c4];
                Bs[c4+0][rr] = v.x; Bs[c4+1][rr] = v.y; Bs[c4+2][rr] = v.z; Bs[c4+3][rr] = v.w;
            }
            __syncthreads();
            #pragma unroll
            for (int k = 0; k < 32; ++k) {
                const float4 a = *(const float4*)&As[k][ty * 4];
                const float4 b = *(const float4*)&Bs[k][tx * 4];
                acc[0][0] += a.x*b.x; acc[0][1] += a.x*b.y; acc[0][2] += a.x*b.z; acc[0][3] += a.x*b.w;
                acc[1][0] += a.y*b.x; acc[1][1] += a.y*b.y; acc[1][2] += a.y*b.z; acc[1][3] += a.y*b.w;
                acc[2][0] += a.z*b.x; acc[2][1] += a.z*b.y; acc[2][2] += a.z*b.z; acc[2][3] += a.z*b.w;
                acc[3][0] += a.w*b.x; acc[3][1] += a.w*b.y; acc[3][2] += a.w*b.z; acc[3][3] += a.w*b.w;
            }
            __syncthreads();
        }
    }
    #pragma unroll
    for (int i = 0; i < 4; ++i) {
        int gr = m0 + ty * 4 + i;
        if (gr >= NN) continue;
        #pragma unroll
        for (int c = 0; c < 4; ++c) {
            int j = n0 + tx * 4 + c;
            float pre = acc[i][c] + bihL[j] + bhhL[j];
            float g = 1.f / (1.f + __expf(-pre));
            size_t off = (j < 128) ? ((size_t)gr * H + j) : ((size_t)gr * H + (j - 128));
            if (BF) {
                __hip_bfloat16* P = (j < 128) ? (__hip_bfloat16*)Rp : (__hip_bfloat16*)Zp;
                P[off] = __float2bfloat16(g);
            } else {
                float* P = (j < 128) ? (float*)Rp : (float*)Zp;
                P[off] = g;
            }
        }
    }
}

// ---------------- nh: inn, hn GEMMs + GRU epilogue, h updated in place ----------------
// Tile 64 rows x 128 cols; per thread acc_inn[4][8], acc_hn[4][8]. Grid 1563.
__device__ __forceinline__ void fma48(float (&acc)[4][8], const float4& a,
                                      const float4& b0, const float4& b1) {
    acc[0][0]+=a.x*b0.x; acc[0][1]+=a.x*b0.y; acc[0][2]+=a.x*b0.z; acc[0][3]+=a.x*b0.w;
    acc[0][4]+=a.x*b1.x; acc[0][5]+=a.x*b1.y; acc[0][6]+=a.x*b1.z; acc[0][7]+=a.x*b1.w;
    acc[1][0]+=a.y*b0.x; acc[1][1]+=a.y*b0.y; acc[1][2]+=a.y*b0.z; acc[1][3]+=a.y*b0.w;
    acc[1][4]+=a.y*b1.x; acc[1][5]+=a.y*b1.y; acc[1][6]+=a.y*b1.z; acc[1][7]+=a.y*b1.w;
    acc[2][0]+=a.z*b0.x; acc[2][1]+=a.z*b0.y; acc[2][2]+=a.z*b0.z; acc[2][3]+=a.z*b0.w;
    acc[2][4]+=a.z*b1.x; acc[2][5]+=a.z*b1.y; acc[2][6]+=a.z*b1.z; acc[2][7]+=a.z*b1.w;
    acc[3][0]+=a.w*b0.x; acc[3][1]+=a.w*b0.y; acc[3][2]+=a.w*b0.z; acc[3][3]+=a.w*b0.w;
    acc[3][4]+=a.w*b1.x; acc[3][5]+=a.w*b1.y; acc[3][6]+=a.w*b1.z; acc[3][7]+=a.w*b1.w;
}

template<bool BF>
__global__ __launch_bounds__(256) void nh_kernel(
    const float* __restrict__ inc,
    const float* __restrict__ res, const int* __restrict__ residx,
    float* __restrict__ h,
    const float* __restrict__ Wih, int ldb,
    const float* __restrict__ Whh,
    const float* __restrict__ bihL, const float* __restrict__ bhhL,
    const void* __restrict__ Rp, const void* __restrict__ Zp)
{
    __shared__ float As[32][68];
    __shared__ float Bs[32][132];
    int tid = threadIdx.x, tx = tid & 15, ty = tid >> 4;
    int m0 = blockIdx.x * 64;
    float ai[4][8] = {};   // inn
    float ah[4][8] = {};   // hn
    int nparts = res ? 3 : 2;
    for (int p = 0; p < nparts; ++p) {
        const float* A; const int* idx = nullptr; const float* B;
        int bs; int toAh;
        if (p == 0)           { A = h;   B = Whh + 256 * 128;      bs = 128; toAh = 1; }
        else if (p == 1)      { A = inc; B = Wih + (size_t)256 * ldb;       bs = ldb; toAh = 0; }
        else                  { A = res; idx = residx; B = Wih + (size_t)256 * ldb + 128; bs = ldb; toAh = 0; }
        for (int k0 = 0; k0 < 128; k0 += 32) {
            #pragma unroll
            for (int q = 0; q < 2; ++q) {
                int id2 = q * 256 + tid, rr = id2 >> 3, c4 = (id2 & 7) << 2;
                int gr = m0 + rr;
                float4 v = make_float4(0.f, 0.f, 0.f, 0.f);
                if (gr < NN) {
                    const float* base = idx ? A + (size_t)idx[gr] * H : A + (size_t)gr * H;
                    v = *(const float4*)&base[k0 + c4];
                }
                As[c4+0][rr] = v.x; As[c4+1][rr] = v.y; As[c4+2][rr] = v.z; As[c4+3][rr] = v.w;
            }
            #pragma unroll
            for (int q = 0; q < 4; ++q) {
                int id2 = q * 256 + tid, rr = id2 >> 3, c4 = (id2 & 7) << 2;   // rr 0..127 (gate col j)
                float4 v = *(const float4*)&B[(size_t)rr * bs + k0 + c4];
                Bs[c4+0][rr] = v.x; Bs[c4+1][rr] = v.y; Bs[c4+2][rr] = v.z; Bs[c4+3][rr] = v.w;
            }
            __syncthreads();
            if (toAh) {
                #pragma unroll
                for (int k = 0; k < 32; ++k) {
                    const float4 a  = *(const float4*)&As[k][ty * 4];
                    const float4 b0 = *(const float4*)&Bs[k][tx * 8];
                    const float4 b1 = *(const float4*)&Bs[k][tx * 8 + 4];
                    fma48(ah, a, b0, b1);
                }
            } else {
                #pragma unroll
                for (int k = 0; k < 32; ++k) {
                    const float4 a  = *(const float4*)&As[k][ty * 4];
                    const float4 b0 = *(const float4*)&Bs[k][tx * 8];
                    const float4 b1 = *(const float4*)&Bs[k][tx * 8 + 4];
                    fma48(ai, a, b0, b1);
                }
            }
            __syncthreads();
        }
    }
    // GRU epilogue
    #pragma unroll
    for (int i = 0; i < 4; ++i) {
        int gr = m0 + ty * 4 + i;
        if (gr >= NN) continue;
        size_t rowb = (size_t)gr * H + tx * 8;
        float4 h0 = *(const float4*)&h[rowb];
        float4 h1 = *(const float4*)&h[rowb + 4];
        float ho[8] = {h0.x, h0.y, h0.z, h0.w, h1.x, h1.y, h1.z, h1.w};
        float o[8];
        #pragma unroll
        for (int c = 0; c < 8; ++c) {
            int j = tx * 8 + c;
            float r, z;
            if (BF) {
                r = __bfloat162float(((const __hip_bfloat16*)Rp)[rowb + c]);
                z = __bfloat162float(((const __hip_bfloat16*)Zp)[rowb + c]);
            } else {
                r = ((const float*)Rp)[rowb + c];
                z = ((const float*)Zp)[rowb + c];
            }
            float n = tanhf(ai[i][c] + bihL[256 + j] + r * (ah[i][c] + bhhL[256 + j]));
            o[c] = (1.f - z) * n + z * ho[c];
        }
        *(float4*)&h[rowb]     = make_float4(o[0], o[1], o[2], o[3]);
        *(float4*)&h[rowb + 4] = make_float4(o[4], o[5], o[6], o[7]);
    }
}

// ---------------- output gathers ----------------
__global__ void out_gather(const float* __restrict__ h, const int* __restrict__ idx,
                           float* __restrict__ out, int n) {
    int g = blockIdx.x * 256 + threadIdx.x;
    if (g >= n * 64) return;
    int v = g >> 6, j2 = (g & 63) << 1;
    *(float2*)&out[(size_t)v * H + j2] = *(const float2*)&h[(size_t)idx[v] * H + j2];
}

extern "C" void kernel_launch(void* const* d_in, const int* in_sizes, int n_in,
                              void* d_out, int out_size, void* d_ws, size_t ws_size,
                              hipStream_t stream) {
    const int*   ids    = (const int*)d_in[0];
    const int*   ast    = (const int*)d_in[1];
    const int*   mst    = (const int*)d_in[2];
    const int*   varpos = (const int*)d_in[3];
    const int*   predid = (const int*)d_in[4];
    const float* emb    = (const float*)d_in[5];
    const float* msg_W  = (const float*)d_in[6];   // [4][4][128][128]
    const float* msg_b  = (const float*)d_in[7];   // [4][4][128]
    const float* Wih_a  = (const float*)d_in[8];   // [2][384][128]
    const float* Wih_b  = (const float*)d_in[9];   // [2][384][256]
    const float* Whh    = (const float*)d_in[10];  // [4][384][128]
    const float* bih    = (const float*)d_in[11];  // [4][384]
    const float* bhh    = (const float*)d_in[12];  // [4][384]

    float* out = (float*)d_out;
    float* h   = out;                         // final h IS output 0

    // CSR ints in d_out tail (dead before final out_gathers overwrite)
    int* ibase = (int*)(out + NH);
    int* deg4  = ibase;                       // 400000
    int* rp4   = ibase + 400000;              // 400001
    int* cnt4  = ibase + 800001;              // 400000
    int* col   = ibase + 1200001;             // 240000
    int* part  = ibase + 1440001;             // 256

    if (ws_size < (size_t)3 * NH * sizeof(float)) return;
    float* W   = (float*)d_ws;
    float* s1  = W;                           // h after layer 0 (residual for layer 3)
    float* inc = W + NH;
    float* agg = W + 2 * (size_t)NH;

    // r/z gate storage: fp32 if workspace allows (r in agg, z in W+3NH), else bf16 packed in agg
    bool rz32 = ws_size >= (size_t)4 * NH * sizeof(float);
    void* Rp = (void*)agg;
    void* Zp = rz32 ? (void*)(W + 3 * (size_t)NH) : (void*)(((__hip_bfloat16*)agg) + NH);

    embed_kernel<<<25000, 256, 0, stream>>>(ids, emb, h);

    hipMemsetAsync(deg4, 0, N4 * sizeof(int), stream);
    hipMemsetAsync(cnt4, 0, N4 * sizeof(int), stream);
    count4_kernel<<<(E_TOT + 255) / 256, 256, 0, stream>>>(ast, mst, deg4);
    scan1b<<<196, 256, 0, stream>>>(deg4, rp4, part, N4);
    scan2<<<1, 256, 0, stream>>>(part, 196);
    scan3b<<<1563, 256, 0, stream>>>(rp4, part, N4, E_TOT);
    fill4_kernel<<<(E_TOT + 255) / 256, 256, 0, stream>>>(ast, mst, rp4, cnt4, col);

    const int LT[4] = {5, 2, 5, 2};
    for (int layer = 0; layer < 4; ++layer) {
        const float* WihL; int ldb;
        const float* res; const int* ridx;
        if      (layer == 0) { WihL = Wih_a;                   ldb = 128; res = nullptr; ridx = nullptr; }
        else if (layer == 1) { WihL = Wih_b;                   ldb = 256; res = emb;     ridx = ids;     }
        else if (layer == 2) { WihL = Wih_a + (size_t)384*128; ldb = 128; res = nullptr; ridx = nullptr; }
        else                 { WihL = Wih_b + (size_t)384*256; ldb = 256; res = s1;      ridx = nullptr; }
        const float* WhhL = Whh + (size_t)layer * 384 * 128;
        const float* bihL = bih + layer * 384;
        const float* bhhL = bhh + layer * 384;
        const float* mbL  = msg_b + (size_t)layer * 512;

        for (int ts = 0; ts < LT[layer]; ++ts) {
            init_inc<<<25000, 256, 0, stream>>>(deg4, mbL, inc);
            for (int e = 0; e < 4; ++e) {
                gather_agg<<<25000, 256, 0, stream>>>(h, rp4, col, e, agg);
                gemm_acc<<<dim3(1563, 2), 256, 0, stream>>>(
                    agg, msg_W + ((size_t)layer * 4 + e) * 128 * 128, inc, NN);
            }
            if (rz32) {
                rz_kernel<false><<<dim3(1563, 4), 256, 0, stream>>>(
                    inc, res, ridx, h, WihL, ldb, WhhL, bihL, bhhL, Rp, Zp);
                nh_kernel<false><<<1563, 256, 0, stream>>>(
                    inc, res, ridx, h, WihL, ldb, WhhL, bihL, bhhL, Rp, Zp);
            } else {
                rz_kernel<true><<<dim3(1563, 4), 256, 0, stream>>>(
                    inc, res, ridx, h, WihL, ldb, WhhL, bihL, bhhL, Rp, Zp);
                nh_kernel<true><<<1563, 256, 0, stream>>>(
                    inc, res, ridx, h, WihL, ldb, WhhL, bihL, bhhL, Rp, Zp);
            }
        }
        if (layer == 0)
            hipMemcpyAsync(s1, h, (size_t)NH * sizeof(float), hipMemcpyDeviceToDevice, stream);
    }

    out_gather<<<(NV * 64 + 255) / 256, 256, 0, stream>>>(h, varpos, out + NH, NV);
    out_gather<<<(NP * 64 + 255) / 256, 256, 0, stream>>>(h, predid, out + NH + (size_t)NV * H, NP);
}

// Round 6
// 6021.244 us; speedup vs baseline: 64.4789x; 1.7357x over previous
//
#include <hip/hip_runtime.h>
#include <math.h>

#define H 128
#define NN 100000
#define E_AST 100000
#define E_MST 20000
#define E_TOT 240000
#define NV 30000
#define NP 8000
#define N4 400000
#define NH 12800000   // NN * H

typedef unsigned short ushort_t;
typedef __attribute__((ext_vector_type(8))) unsigned short us8;
typedef _Float16 half8 __attribute__((ext_vector_type(8)));
typedef __attribute__((ext_vector_type(4))) float f32x4;

__device__ __forceinline__ unsigned short f2h(float f) {
    _Float16 h = (_Float16)f;
    return __builtin_bit_cast(unsigned short, h);
}
__device__ __forceinline__ float h2f(unsigned short u) {
    return (float)__builtin_bit_cast(_Float16, u);
}
__device__ __forceinline__ void fsplit(float x, unsigned short& hi, unsigned short& lo) {
    _Float16 a = (_Float16)x;
    _Float16 b = (_Float16)(x - (float)a);
    hi = __builtin_bit_cast(unsigned short, a);
    lo = __builtin_bit_cast(unsigned short, b);
}

#define GLD16(gsrc, ldst) __builtin_amdgcn_global_load_lds( \
    (const __attribute__((address_space(1))) unsigned int*)(gsrc), \
    (__attribute__((address_space(3))) unsigned int*)(ldst), 16, 0, 0)

// ---------------- embedding -> h fp32 ----------------
__global__ void embed_kernel(const int* __restrict__ ids, const float* __restrict__ emb,
                             float* __restrict__ h) {
    int g = blockIdx.x * 256 + threadIdx.x;
    if (g >= NN * 64) return;
    int i = g >> 6, j2 = (g & 63) << 1;
    *(float2*)&h[(size_t)i * H + j2] = *(const float2*)&emb[(size_t)ids[i] * H + j2];
}

// ---------------- CSR build over keys (tgt*4 + e), payload src ----------------
__device__ inline void edge_decode(int t, const int* __restrict__ ast, const int* __restrict__ mst,
                                   int& e, int& src, int& tgt) {
    if (t < E_AST)                 { e = 0; src = ast[2*t];     tgt = ast[2*t+1]; }
    else if (t < 2*E_AST)          { int i = t - E_AST;         e = 1; src = ast[2*i+1]; tgt = ast[2*i]; }
    else if (t < 2*E_AST + E_MST)  { int i = t - 2*E_AST;       e = 2; src = mst[2*i];   tgt = mst[2*i+1]; }
    else                           { int i = t - 2*E_AST-E_MST; e = 3; src = mst[2*i+1]; tgt = mst[2*i]; }
}

__global__ void count4_kernel(const int* __restrict__ ast, const int* __restrict__ mst,
                              int* __restrict__ deg4) {
    int t = blockIdx.x * 256 + threadIdx.x;
    if (t >= E_TOT) return;
    int e, src, tgt; edge_decode(t, ast, mst, e, src, tgt);
    atomicAdd(&deg4[tgt * 4 + e], 1);
}

__global__ void scan1b(const int* __restrict__ deg, int* __restrict__ excl,
                       int* __restrict__ partial, int n) {
    __shared__ int sm[256];
    int t = threadIdx.x, b = blockIdx.x;
    int base = b * 2048 + t * 8;
    int v[8]; int s = 0;
    #pragma unroll
    for (int i = 0; i < 8; ++i) { v[i] = (base + i < n) ? deg[base + i] : 0; s += v[i]; }
    sm[t] = s;
    __syncthreads();
    for (int off = 1; off < 256; off <<= 1) {
        int x = (t >= off) ? sm[t - off] : 0;
        __syncthreads();
        sm[t] += x;
        __syncthreads();
    }
    int run = sm[t] - s;
    if (t == 255) partial[b] = sm[255];
    #pragma unroll
    for (int i = 0; i < 8; ++i) {
        if (base + i < n) { excl[base + i] = run; run += v[i]; }
    }
}

__global__ void scan2(int* __restrict__ partial, int nb) {
    __shared__ int sm[256];
    int t = threadIdx.x;
    int v = (t < nb) ? partial[t] : 0;
    sm[t] = v;
    __syncthreads();
    for (int off = 1; off < 256; off <<= 1) {
        int x = (t >= off) ? sm[t - off] : 0;
        __syncthreads();
        sm[t] += x;
        __syncthreads();
    }
    if (t < nb) partial[t] = sm[t] - v;
}

__global__ void scan3b(int* __restrict__ rp, const int* __restrict__ partial, int n, int etot) {
    int i = blockIdx.x * 256 + threadIdx.x;
    if (i < n) rp[i] += partial[i >> 11];
    if (i == n) rp[n] = etot;
}

__global__ void fill4_kernel(const int* __restrict__ ast, const int* __restrict__ mst,
                             const int* __restrict__ rp4, int* __restrict__ cnt4,
                             int* __restrict__ col) {
    int t = blockIdx.x * 256 + threadIdx.x;
    if (t >= E_TOT) return;
    int e, src, tgt; edge_decode(t, ast, mst, e, src, tgt);
    int key = tgt * 4 + e;
    int slot = rp4[key] + atomicAdd(&cnt4[key], 1);
    col[slot] = src;
}

// ---------------- weight prep: fp16 hi/lo splits ----------------
__global__ void prep_wmsg2(const float* __restrict__ W, ushort_t* __restrict__ hi,
                           ushort_t* __restrict__ lo) {
    int i = blockIdx.x * 256 + threadIdx.x;
    if (i >= 262144) return;
    fsplit(W[i], hi[i], lo[i]);
}

// B1 rows 2j/2j+1 = r_j/z_j over K=[Wih | Whh]; B2 rows 2j/2j+1 = inn_j(Wih,0) / hn_j(0,Whh)
__global__ void prep_B2(const float* __restrict__ Wih_a, const float* __restrict__ Wih_b,
                        const float* __restrict__ Whh,
                        ushort_t* __restrict__ B1h, ushort_t* __restrict__ B1l,
                        ushort_t* __restrict__ B2h, ushort_t* __restrict__ B2l) {
    int i = blockIdx.x * 256 + threadIdx.x;
    if (i >= 327680) return;
    int l, off, K;
    if (i < 65536)       { l = 0; off = 0;      K = 256; }
    else if (i < 163840) { l = 1; off = 65536;  K = 384; }
    else if (i < 229376) { l = 2; off = 163840; K = 256; }
    else                 { l = 3; off = 229376; K = 384; }
    int Kx = K - 128;
    const float* Wih = (l & 1) ? (Wih_b + (size_t)(l >> 1) * 384 * 256)
                               : (Wih_a + (size_t)(l >> 1) * 384 * 128);
    const float* WhhL = Whh + (size_t)l * 384 * 128;
    int rem = i - off;
    int row = rem / K, k = rem - row * K;
    int j = row >> 1, s = row & 1;
    int g1 = s * 128 + j;
    float v1 = (k < Kx) ? Wih[(size_t)g1 * Kx + k] : WhhL[(size_t)g1 * 128 + (k - Kx)];
    fsplit(v1, B1h[i], B1l[i]);
    int g2 = 256 + j;
    float v2;
    if (s == 0) v2 = (k < Kx) ? Wih[(size_t)g2 * Kx + k] : 0.f;
    else        v2 = (k < Kx) ? 0.f : WhhL[(size_t)g2 * 128 + (k - Kx)];
    fsplit(v2, B2h[i], B2l[i]);
}

// ---------------- msg GEMM: T[NN][128] = h @ W_e^T (split fp16, 3 products) ----------------
__global__ __launch_bounds__(256) void msg_gemm(
    const float* __restrict__ h, const ushort_t* __restrict__ Whi,
    const ushort_t* __restrict__ Wlo, float* __restrict__ T)
{
    __shared__ ushort_t Ahi[128 * 64], Alo[128 * 64], Bs[128 * 64];
    const int tid = threadIdx.x, w = tid >> 6, l = tid & 63;
    const int m0 = blockIdx.x * 128;
    const int wm = w >> 1, wn = w & 1;
    f32x4 acc[4][4];
    #pragma unroll
    for (int a = 0; a < 4; ++a)
        #pragma unroll
        for (int b = 0; b < 4; ++b) acc[a][b] = (f32x4){0.f, 0.f, 0.f, 0.f};

    for (int kt = 0; kt < 2; ++kt) {
        const int kk = kt * 64;
        // A: reg-stage fp32 -> hi/lo, coalesced (2 lanes per row, 128B each)
        {
            int r = tid >> 1, half = tid & 1;
            int grow = m0 + r; if (grow >= NN) grow = NN - 1;
            const float* s = h + (size_t)grow * H + kk + half * 32;
            ushort_t hi32[32], lo32[32];
            #pragma unroll
            for (int q = 0; q < 8; ++q) {
                float4 v = *(const float4*)&s[q * 4];
                fsplit(v.x, hi32[q*4+0], lo32[q*4+0]);
                fsplit(v.y, hi32[q*4+1], lo32[q*4+1]);
                fsplit(v.z, hi32[q*4+2], lo32[q*4+2]);
                fsplit(v.w, hi32[q*4+3], lo32[q*4+3]);
            }
            #pragma unroll
            for (int gq = 0; gq < 4; ++gq) {
                int g = half * 4 + gq;
                int slot = g ^ (r & 7);
                *(us8*)&Ahi[r * 64 + slot * 8] = *(us8*)&hi32[gq * 8];
                *(us8*)&Alo[r * 64 + slot * 8] = *(us8*)&lo32[gq * 8];
            }
        }
        #pragma unroll
        for (int q = 0; q < 4; ++q) {
            int row8 = w * 4 + q;
            const ushort_t* gs = Whi + (size_t)(row8 * 8 + (l >> 3)) * 128 + kk + ((l & 7) ^ (l >> 3)) * 8;
            GLD16(gs, &Bs[row8 * 512]);
        }
        __syncthreads();
        #pragma unroll
        for (int fk = 0; fk < 2; ++fk) {
            half8 ah[4], al[4], bh[4];
            #pragma unroll
            for (int fm = 0; fm < 4; ++fm) {
                int row = wm * 64 + fm * 16 + (l & 15);
                int slot = (fk * 4 + (l >> 4)) ^ (row & 7);
                ah[fm] = *(const half8*)&Ahi[row * 64 + slot * 8];
                al[fm] = *(const half8*)&Alo[row * 64 + slot * 8];
            }
            #pragma unroll
            for (int fn = 0; fn < 4; ++fn) {
                int row = wn * 64 + fn * 16 + (l & 15);
                int slot = (fk * 4 + (l >> 4)) ^ (row & 7);
                bh[fn] = *(const half8*)&Bs[row * 64 + slot * 8];
            }
            #pragma unroll
            for (int fm = 0; fm < 4; ++fm)
                #pragma unroll
                for (int fn = 0; fn < 4; ++fn) {
                    acc[fm][fn] = __builtin_amdgcn_mfma_f32_16x16x32_f16(ah[fm], bh[fn], acc[fm][fn], 0, 0, 0);
                    acc[fm][fn] = __builtin_amdgcn_mfma_f32_16x16x32_f16(al[fm], bh[fn], acc[fm][fn], 0, 0, 0);
                }
        }
        __syncthreads();
        #pragma unroll
        for (int q = 0; q < 4; ++q) {
            int row8 = w * 4 + q;
            const ushort_t* gs = Wlo + (size_t)(row8 * 8 + (l >> 3)) * 128 + kk + ((l & 7) ^ (l >> 3)) * 8;
            GLD16(gs, &Bs[row8 * 512]);
        }
        __syncthreads();
        #pragma unroll
        for (int fk = 0; fk < 2; ++fk) {
            half8 ah[4], bl[4];
            #pragma unroll
            for (int fm = 0; fm < 4; ++fm) {
                int row = wm * 64 + fm * 16 + (l & 15);
                int slot = (fk * 4 + (l >> 4)) ^ (row & 7);
                ah[fm] = *(const half8*)&Ahi[row * 64 + slot * 8];
            }
            #pragma unroll
            for (int fn = 0; fn < 4; ++fn) {
                int row = wn * 64 + fn * 16 + (l & 15);
                int slot = (fk * 4 + (l >> 4)) ^ (row & 7);
                bl[fn] = *(const half8*)&Bs[row * 64 + slot * 8];
            }
            #pragma unroll
            for (int fm = 0; fm < 4; ++fm)
                #pragma unroll
                for (int fn = 0; fn < 4; ++fn)
                    acc[fm][fn] = __builtin_amdgcn_mfma_f32_16x16x32_f16(ah[fm], bl[fn], acc[fm][fn], 0, 0, 0);
        }
        __syncthreads();
    }
    #pragma unroll
    for (int fm = 0; fm < 4; ++fm)
        #pragma unroll
        for (int fn = 0; fn < 4; ++fn) {
            int cc = wn * 64 + fn * 16 + (l & 15);
            #pragma unroll
            for (int rg = 0; rg < 4; ++rg) {
                int row = m0 + wm * 64 + fm * 16 + (l >> 4) * 4 + rg;
                if (row < NN) T[(size_t)row * H + cc] = acc[fm][fn][rg];
            }
        }
}

// ---------------- gather over CSR quarter e: inc fp32 (+bias init at e==0) ----------------
__global__ void gather_q(const float* __restrict__ T, const int* __restrict__ rp4,
                         const int* __restrict__ col, const int* __restrict__ deg4,
                         const float* __restrict__ mb, float* __restrict__ inc, int e) {
    int wv = threadIdx.x >> 6, l = threadIdx.x & 63;
    int t = blockIdx.x * 4 + wv;
    if (t >= NN) return;
    int c2 = l * 2;
    float2 a;
    if (e == 0) {
        a = make_float2(0.f, 0.f);
        #pragma unroll
        for (int e4 = 0; e4 < 4; ++e4) {
            float d = (float)deg4[t * 4 + e4];
            a.x += d * mb[e4 * H + c2];
            a.y += d * mb[e4 * H + c2 + 1];
        }
    } else {
        a = *(const float2*)&inc[(size_t)t * H + c2];
    }
    int s0 = rp4[4 * t + e], s1 = rp4[4 * t + e + 1];
    for (int s = s0; s < s1; ++s) {
        float2 v = *(const float2*)&T[(size_t)col[s] * H + c2];
        a.x += v.x; a.y += v.y;
    }
    *(float2*)&inc[(size_t)t * H + c2] = a;
}

// ---------------- gate GEMM: 64x256 tile, row-exclusive blocks ----------------
// MODE 1: r,z -> rzhi pairs + zlo.  MODE 2: inn/hn + GRU epilogue -> h fp32 in place.
// CFG 0: [inc,h] K=256; 1: [inc,emb,h] K=384; 2: [inc,s1,h] K=384
template<int MODE, int CFG>
__global__ __launch_bounds__(256) void gate_gemm(
    const float* __restrict__ inc, float* __restrict__ h,
    const ushort_t* __restrict__ s1h, const float* __restrict__ emb, const int* __restrict__ ids,
    const ushort_t* __restrict__ Bhi, const ushort_t* __restrict__ Blo,
    ushort_t* __restrict__ rzhi, ushort_t* __restrict__ zlo,
    const float* __restrict__ bihL, const float* __restrict__ bhhL)
{
    constexpr int NPARTS = (CFG == 0) ? 2 : 3;
    constexpr int K = NPARTS * 128;
    __shared__ ushort_t Ahi[64 * 64], Alo[64 * 64], Bs[256 * 64];
    const int tid = threadIdx.x, w = tid >> 6, l = tid & 63;
    const int m0 = blockIdx.x * 64;
    f32x4 acc[4][4];
    #pragma unroll
    for (int a = 0; a < 4; ++a)
        #pragma unroll
        for (int b = 0; b < 4; ++b) acc[a][b] = (f32x4){0.f, 0.f, 0.f, 0.f};

    for (int kt = 0; kt < NPARTS * 2; ++kt) {
        const int p = kt >> 1;
        const int kk = (kt & 1) * 64;
        const int kb = p * 128 + kk;
        const bool isInc = (p == 0);
        const bool isH   = (p == NPARTS - 1);
        const bool split = isInc || isH;

        if (split || CFG == 1) {
            // fp32 source, reg-split staging; coalesced: 4 lanes per row, 64B each
            int r = tid >> 2, half = tid & 3;
            int grow = m0 + r; if (grow >= NN) grow = NN - 1;
            const float* src;
            if (isInc)      src = inc + (size_t)grow * H;
            else if (isH)   src = h + (size_t)grow * H;
            else            src = emb + (size_t)ids[grow] * H;   // CFG==1 middle
            src += kk + half * 16;
            ushort_t hi16[16], lo16[16];
            #pragma unroll
            for (int q = 0; q < 4; ++q) {
                float4 v = *(const float4*)&src[q * 4];
                fsplit(v.x, hi16[q*4+0], lo16[q*4+0]);
                fsplit(v.y, hi16[q*4+1], lo16[q*4+1]);
                fsplit(v.z, hi16[q*4+2], lo16[q*4+2]);
                fsplit(v.w, hi16[q*4+3], lo16[q*4+3]);
            }
            #pragma unroll
            for (int gq = 0; gq < 2; ++gq) {
                int g = half * 2 + gq;
                int slot = g ^ (r & 7);
                *(us8*)&Ahi[r * 64 + slot * 8] = *(us8*)&hi16[gq * 8];
                if (split) *(us8*)&Alo[r * 64 + slot * 8] = *(us8*)&lo16[gq * 8];
            }
        } else {
            // CFG==2 middle: s1 fp16 single via GLD16
            #pragma unroll
            for (int q = 0; q < 2; ++q) {
                int row8 = w * 2 + q;
                int row = row8 * 8 + (l >> 3);
                int grow = m0 + row; if (grow >= NN) grow = NN - 1;
                const ushort_t* gs = s1h + (size_t)grow * H + kk + ((l & 7) ^ (l >> 3)) * 8;
                GLD16(gs, &Ahi[row8 * 512]);
            }
        }
        #pragma unroll
        for (int q = 0; q < 8; ++q) {
            int row8 = w * 8 + q;
            const ushort_t* gs = Bhi + (size_t)(row8 * 8 + (l >> 3)) * K + kb + ((l & 7) ^ (l >> 3)) * 8;
            GLD16(gs, &Bs[row8 * 512]);
        }
        __syncthreads();
        #pragma unroll
        for (int fk = 0; fk < 2; ++fk) {
            half8 ah[4], al[4], bh[4];
            #pragma unroll
            for (int fm = 0; fm < 4; ++fm) {
                int row = fm * 16 + (l & 15);
                int slot = (fk * 4 + (l >> 4)) ^ (row & 7);
                ah[fm] = *(const half8*)&Ahi[row * 64 + slot * 8];
                if (split) al[fm] = *(const half8*)&Alo[row * 64 + slot * 8];
            }
            #pragma unroll
            for (int fn = 0; fn < 4; ++fn) {
                int row = w * 64 + fn * 16 + (l & 15);
                int slot = (fk * 4 + (l >> 4)) ^ (row & 7);
                bh[fn] = *(const half8*)&Bs[row * 64 + slot * 8];
            }
            #pragma unroll
            for (int fm = 0; fm < 4; ++fm)
                #pragma unroll
                for (int fn = 0; fn < 4; ++fn) {
                    acc[fm][fn] = __builtin_amdgcn_mfma_f32_16x16x32_f16(ah[fm], bh[fn], acc[fm][fn], 0, 0, 0);
                    if (split)
                        acc[fm][fn] = __builtin_amdgcn_mfma_f32_16x16x32_f16(al[fm], bh[fn], acc[fm][fn], 0, 0, 0);
                }
        }
        __syncthreads();
        #pragma unroll
        for (int q = 0; q < 8; ++q) {
            int row8 = w * 8 + q;
            const ushort_t* gs = Blo + (size_t)(row8 * 8 + (l >> 3)) * K + kb + ((l & 7) ^ (l >> 3)) * 8;
            GLD16(gs, &Bs[row8 * 512]);
        }
        __syncthreads();
        #pragma unroll
        for (int fk = 0; fk < 2; ++fk) {
            half8 ah[4], bl[4];
            #pragma unroll
            for (int fm = 0; fm < 4; ++fm) {
                int row = fm * 16 + (l & 15);
                int slot = (fk * 4 + (l >> 4)) ^ (row & 7);
                ah[fm] = *(const half8*)&Ahi[row * 64 + slot * 8];
            }
            #pragma unroll
            for (int fn = 0; fn < 4; ++fn) {
                int row = w * 64 + fn * 16 + (l & 15);
                int slot = (fk * 4 + (l >> 4)) ^ (row & 7);
                bl[fn] = *(const half8*)&Bs[row * 64 + slot * 8];
            }
            #pragma unroll
            for (int fm = 0; fm < 4; ++fm)
                #pragma unroll
                for (int fn = 0; fn < 4; ++fn)
                    acc[fm][fn] = __builtin_amdgcn_mfma_f32_16x16x32_f16(ah[fm], bl[fn], acc[fm][fn], 0, 0, 0);
        }
        __syncthreads();
    }

    // epilogue
    #pragma unroll
    for (int fm = 0; fm < 4; ++fm)
        #pragma unroll
        for (int fn = 0; fn < 4; ++fn) {
            int cc = w * 64 + fn * 16 + (l & 15);
            int j = cc >> 1, s = cc & 1;
            #pragma unroll
            for (int rg = 0; rg < 4; ++rg) {
                int row = m0 + fm * 16 + (l >> 4) * 4 + rg;
                float v = acc[fm][fn][rg];
                if (MODE == 1) {
                    float pre = v + bihL[s * 128 + j] + bhhL[s * 128 + j];
                    float g = 1.f / (1.f + __expf(-pre));
                    unsigned short gh = f2h(g);
                    int ot = __shfl_xor((int)gh, 1);
                    if (row < NN) {
                        if (s == 0)
                            *(unsigned*)&rzhi[(size_t)row * 256 + cc] =
                                (unsigned)gh | ((unsigned)(unsigned short)ot << 16);
                        else
                            zlo[(size_t)row * H + j] = f2h(g - h2f(gh));
                    }
                } else {
                    float self = v + (s ? bhhL[256 + j] : bihL[256 + j]);
                    float other = __shfl_xor(self, 1);
                    if (s == 0 && row < NN) {
                        unsigned rzp = *(const unsigned*)&rzhi[(size_t)row * 256 + cc];
                        float r = h2f((unsigned short)(rzp & 0xffff));
                        float z = h2f((unsigned short)(rzp >> 16)) + h2f(zlo[(size_t)row * H + j]);
                        float n = tanhf(self + r * other);
                        float hold = h[(size_t)row * H + j];
                        h[(size_t)row * H + j] = (1.f - z) * n + z * hold;
                    }
                }
            }
        }
}

// ---------------- s1 snapshot: h fp32 -> fp16 ----------------
__global__ void h2h16(const float* __restrict__ h, ushort_t* __restrict__ s1h) {
    int g = blockIdx.x * 256 + threadIdx.x;
    if (g >= NN * 64) return;
    float2 v = *(const float2*)&h[(size_t)g * 2];
    unsigned pk = (unsigned)f2h(v.x) | ((unsigned)f2h(v.y) << 16);
    *(unsigned*)&s1h[(size_t)g * 2] = pk;
}

// ---------------- output gathers ----------------
__global__ void out_gather(const float* __restrict__ h, const int* __restrict__ idx,
                           float* __restrict__ out, int n) {
    int g = blockIdx.x * 256 + threadIdx.x;
    if (g >= n * 64) return;
    int v = g >> 6, j2 = (g & 63) << 1;
    *(float2*)&out[(size_t)v * H + j2] = *(const float2*)&h[(size_t)idx[v] * H + j2];
}

extern "C" void kernel_launch(void* const* d_in, const int* in_sizes, int n_in,
                              void* d_out, int out_size, void* d_ws, size_t ws_size,
                              hipStream_t stream) {
    const int*   ids    = (const int*)d_in[0];
    const int*   ast    = (const int*)d_in[1];
    const int*   mst    = (const int*)d_in[2];
    const int*   varpos = (const int*)d_in[3];
    const int*   predid = (const int*)d_in[4];
    const float* emb    = (const float*)d_in[5];
    const float* msg_W  = (const float*)d_in[6];   // [4][4][128][128]
    const float* msg_b  = (const float*)d_in[7];   // [4][4][128]
    const float* Wih_a  = (const float*)d_in[8];
    const float* Wih_b  = (const float*)d_in[9];
    const float* Whh    = (const float*)d_in[10];
    const float* bih    = (const float*)d_in[11];
    const float* bhh    = (const float*)d_in[12];

    float* out = (float*)d_out;
    float* h   = out;                              // h fp32 lives in d_out

    // d_out tail: CSR ints + fp16 weight splits (dead before final out_gathers)
    int* ibase = (int*)(out + NH);
    int* deg4  = ibase;                            // 400000
    int* rp4   = ibase + 400000;                   // 400001
    int* cnt4  = ibase + 800001;                   // 400000
    int* col   = ibase + 1200001;                  // 240000
    int* part  = ibase + 1440001;                  // 256
    ushort_t* WT   = (ushort_t*)(ibase + 1500000);
    ushort_t* wmh  = WT;                           // 262144
    ushort_t* wml  = WT + 262144;
    ushort_t* B1h  = WT + 524288;                  // 327680
    ushort_t* B1l  = WT + 851968;
    ushort_t* B2h  = WT + 1179648;
    ushort_t* B2l  = WT + 1507328;                 // end 1835008 ush

    // workspace: exactly 153.6 MB (proven safe)
    if (ws_size < (size_t)153600000) return;
    char* wsb = (char*)d_ws;
    float*    inc  = (float*)wsb;                          // 51.2 MB [NN][128]
    ushort_t* s1h  = (ushort_t*)(wsb + 51200000);          // 25.6 MB
    float*    T    = (float*)(wsb + 76800000);             // 51.2 MB (msg phase)
    ushort_t* rzhi = (ushort_t*)(wsb + 76800000);          // 51.2 MB (gate phase, shares T)
    ushort_t* zlo  = (ushort_t*)(wsb + 128000000);         // 25.6 MB

    embed_kernel<<<25000, 256, 0, stream>>>(ids, emb, h);

    hipMemsetAsync(deg4, 0, N4 * sizeof(int), stream);
    hipMemsetAsync(cnt4, 0, N4 * sizeof(int), stream);
    count4_kernel<<<(E_TOT + 255) / 256, 256, 0, stream>>>(ast, mst, deg4);
    scan1b<<<196, 256, 0, stream>>>(deg4, rp4, part, N4);
    scan2<<<1, 256, 0, stream>>>(part, 196);
    scan3b<<<1563, 256, 0, stream>>>(rp4, part, N4, E_TOT);
    fill4_kernel<<<(E_TOT + 255) / 256, 256, 0, stream>>>(ast, mst, rp4, cnt4, col);
    prep_wmsg2<<<1024, 256, 0, stream>>>(msg_W, wmh, wml);
    prep_B2<<<1280, 256, 0, stream>>>(Wih_a, Wih_b, Whh, B1h, B1l, B2h, B2l);

    const int LT[4] = {5, 2, 5, 2};
    const int Boff[4] = {0, 65536, 163840, 229376};
    for (int layer = 0; layer < 4; ++layer) {
        const float* bihL = bih + layer * 384;
        const float* bhhL = bhh + layer * 384;
        const float* mbL  = msg_b + (size_t)layer * 512;
        const ushort_t* B1hL = B1h + Boff[layer];
        const ushort_t* B1lL = B1l + Boff[layer];
        const ushort_t* B2hL = B2h + Boff[layer];
        const ushort_t* B2lL = B2l + Boff[layer];

        for (int ts = 0; ts < LT[layer]; ++ts) {
            for (int e = 0; e < 4; ++e) {
                const ushort_t* WhiE = wmh + ((size_t)layer * 4 + e) * 16384;
                const ushort_t* WloE = wml + ((size_t)layer * 4 + e) * 16384;
                msg_gemm<<<782, 256, 0, stream>>>(h, WhiE, WloE, T);
                gather_q<<<25000, 256, 0, stream>>>(T, rp4, col, deg4, mbL, inc, e);
            }
            if (layer == 0 || layer == 2) {
                gate_gemm<1,0><<<1563, 256, 0, stream>>>(inc, h, s1h, emb, ids, B1hL, B1lL, rzhi, zlo, bihL, bhhL);
                gate_gemm<2,0><<<1563, 256, 0, stream>>>(inc, h, s1h, emb, ids, B2hL, B2lL, rzhi, zlo, bihL, bhhL);
            } else if (layer == 1) {
                gate_gemm<1,1><<<1563, 256, 0, stream>>>(inc, h, s1h, emb, ids, B1hL, B1lL, rzhi, zlo, bihL, bhhL);
                gate_gemm<2,1><<<1563, 256, 0, stream>>>(inc, h, s1h, emb, ids, B2hL, B2lL, rzhi, zlo, bihL, bhhL);
            } else {
                gate_gemm<1,2><<<1563, 256, 0, stream>>>(inc, h, s1h, emb, ids, B1hL, B1lL, rzhi, zlo, bihL, bhhL);
                gate_gemm<2,2><<<1563, 256, 0, stream>>>(inc, h, s1h, emb, ids, B2hL, B2lL, rzhi, zlo, bihL, bhhL);
            }
        }
        if (layer == 0)
            h2h16<<<25000, 256, 0, stream>>>(h, s1h);
    }

    out_gather<<<(NV * 64 + 255) / 256, 256, 0, stream>>>(h, varpos, out + NH, NV);
    out_gather<<<(NP * 64 + 255) / 256, 256, 0, stream>>>(h, predid, out + NH + (size_t)NV * H, NP);
}